// Round 1
// baseline (836.705 us; speedup 1.0000x reference)
//
#include <hip/hip_runtime.h>
#include <math.h>

#define D_MODEL 1024
#define NUM_EXP 64
#define B_SZ 16
#define L_SZ 2048

using bf16x8  = __attribute__((ext_vector_type(8))) __bf16;
using floatx4 = __attribute__((ext_vector_type(4))) float;
using ushort8 = __attribute__((ext_vector_type(8))) unsigned short;
using ushort4v = __attribute__((ext_vector_type(4))) unsigned short;

__device__ __forceinline__ unsigned short f2bf(float f) {
    union { float f; unsigned u; } x; x.f = f;
    unsigned r = (x.u + 0x7fffu + ((x.u >> 16) & 1u)) >> 16;
    return (unsigned short)r;
}

// ---------------- f32 -> bf16 convert ----------------
__global__ void k_convert(const float* __restrict__ in, unsigned short* __restrict__ out, int n) {
    int i = (blockIdx.x * blockDim.x + threadIdx.x) * 8;
    if (i >= n) return;
    float4 a = *(const float4*)(in + i);
    float4 b = *(const float4*)(in + i + 4);
    ushort8 r;
    r[0]=f2bf(a.x); r[1]=f2bf(a.y); r[2]=f2bf(a.z); r[3]=f2bf(a.w);
    r[4]=f2bf(b.x); r[5]=f2bf(b.y); r[6]=f2bf(b.z); r[7]=f2bf(b.w);
    *(ushort8*)(out + i) = r;
}

// ---------------- gather q_emb/b_emb rows; qbk[be] = q_row . bk ----------------
__global__ void k_gather(const int* __restrict__ idx, const float* __restrict__ q_emb,
                         const float* __restrict__ b_emb, const float* __restrict__ bk,
                         unsigned short* __restrict__ qexp, float* __restrict__ bias_exp,
                         float* __restrict__ qbk)
{
    int be = blockIdx.x;               // 0 .. B*E-1
    int row = idx[be];
    int t = threadIdx.x;               // 256 threads, 4 floats each = 1024
    const float* qs = q_emb + (long)row * D_MODEL;
    const float* bsrc = b_emb + (long)row * D_MODEL;
    float4 q4 = *(const float4*)(qs + t * 4);
    float4 k4 = *(const float4*)(bk + t * 4);
    float4 b4 = *(const float4*)(bsrc + t * 4);
    ushort4v r; r[0]=f2bf(q4.x); r[1]=f2bf(q4.y); r[2]=f2bf(q4.z); r[3]=f2bf(q4.w);
    *(ushort4v*)(qexp + (long)be * D_MODEL + t * 4) = r;
    *(float4*)(bias_exp + (long)be * D_MODEL + t * 4) = b4;
    float p = q4.x*k4.x + q4.y*k4.y + q4.z*k4.z + q4.w*k4.w;
    #pragma unroll
    for (int o = 32; o > 0; o >>= 1) p += __shfl_down(p, o);
    __shared__ float red[4];
    if ((t & 63) == 0) red[t >> 6] = p;
    __syncthreads();
    if (t == 0) qbk[be] = red[0] + red[1] + red[2] + red[3];
}

// ---------------- GEMM, B^T layout: C = epi( (A[M,K] @ B[N,K]^T) ) ----------------
// v = (acc + rowbias[gm]) * scale + colbias[gn]*(roww?roww[gm]:1) + biasMat[gm,gn]
// flags: bit0 = store bf16, bit1 = sigmoid
__launch_bounds__(256)
__global__ void k_gemm_bt(const unsigned short* __restrict__ A,
                          const unsigned short* __restrict__ Bm,
                          const float* __restrict__ colbias,
                          const float* __restrict__ roww,
                          const float* __restrict__ rowbias,
                          const float* __restrict__ biasMat,
                          void* __restrict__ Cout,
                          int M, int N, int K, float scale, int flags,
                          long sA, long sB, long sC)
{
    __shared__ __align__(16) unsigned short As[64 * 32];
    __shared__ __align__(16) unsigned short Bs[64 * 32];
    const int bz = blockIdx.z;
    const unsigned short* Ab = A + (long)bz * sA;
    const unsigned short* Bb = Bm + (long)bz * sB;
    const int tid = threadIdx.x;
    const int wave = tid >> 6, lane = tid & 63;
    const int m0 = blockIdx.y * 64, n0 = blockIdx.x * 64;
    const int lrow = tid >> 2, lk = (tid & 3) * 8;
    const int q = lane >> 4, mr = lane & 15;

    floatx4 acc[4];
    floatx4 z4 = {0.f, 0.f, 0.f, 0.f};
    #pragma unroll
    for (int j = 0; j < 4; j++) acc[j] = z4;

    const unsigned short* Aptr = Ab + (long)(m0 + lrow) * K + lk;
    const unsigned short* Bptr = Bb + (long)(n0 + lrow) * K + lk;

    for (int k0 = 0; k0 < K; k0 += 32) {
        __syncthreads();
        *(ushort8*)&As[lrow * 32 + lk] = *(const ushort8*)(Aptr + k0);
        *(ushort8*)&Bs[lrow * 32 + lk] = *(const ushort8*)(Bptr + k0);
        __syncthreads();
        bf16x8 af = *(const bf16x8*)&As[(wave * 16 + mr) * 32 + q * 8];
        #pragma unroll
        for (int j = 0; j < 4; j++) {
            bf16x8 bfr = *(const bf16x8*)&Bs[(j * 16 + mr) * 32 + q * 8];
            acc[j] = __builtin_amdgcn_mfma_f32_16x16x32_bf16(af, bfr, acc[j], 0, 0, 0);
        }
    }
    #pragma unroll
    for (int j = 0; j < 4; j++) {
        int gn = n0 + j * 16 + mr;
        float cb = colbias ? colbias[gn] : 0.f;
        #pragma unroll
        for (int r = 0; r < 4; r++) {
            int gm = m0 + wave * 16 + q * 4 + r;
            float v = acc[j][r];
            if (rowbias) v += rowbias[(long)bz * M + gm];
            v *= scale;
            if (colbias) v += roww ? cb * roww[(long)bz * M + gm] : cb;
            if (biasMat) v += biasMat[((long)bz * M + gm) * (long)N + gn];
            if (flags & 2) v = 1.f / (1.f + __expf(-v));
            long cidx = (long)bz * sC + (long)gm * N + gn;
            if (flags & 1) ((unsigned short*)Cout)[cidx] = f2bf(v);
            else           ((float*)Cout)[cidx] = v;
        }
    }
}

// ---------------- GEMM, normal-B layout: C_bf16 = A[M,K] @ B[K,N] ----------------
__launch_bounds__(256)
__global__ void k_gemm_bn(const unsigned short* __restrict__ A,
                          const unsigned short* __restrict__ Bm,
                          unsigned short* __restrict__ Cout,
                          int M, int N, int K,
                          long sA, long sB, long sC)
{
    __shared__ __align__(16) unsigned short As[64 * 32];
    __shared__ __align__(16) unsigned short BsT[64 * 32];
    const int bz = blockIdx.z;
    const unsigned short* Ab = A + (long)bz * sA;
    const unsigned short* Bb = Bm + (long)bz * sB;
    const int tid = threadIdx.x;
    const int wave = tid >> 6, lane = tid & 63;
    const int m0 = blockIdx.y * 64, n0 = blockIdx.x * 64;
    const int lrow = tid >> 2, lk = (tid & 3) * 8;
    const int bkr = tid >> 3, bnc = (tid & 7) * 8;
    const int q = lane >> 4, mr = lane & 15;

    floatx4 acc[4];
    floatx4 z4 = {0.f, 0.f, 0.f, 0.f};
    #pragma unroll
    for (int j = 0; j < 4; j++) acc[j] = z4;

    for (int k0 = 0; k0 < K; k0 += 32) {
        __syncthreads();
        *(ushort8*)&As[lrow * 32 + lk] = *(const ushort8*)(Ab + (long)(m0 + lrow) * K + k0 + lk);
        ushort8 bv = *(const ushort8*)(Bb + (long)(k0 + bkr) * N + n0 + bnc);
        #pragma unroll
        for (int jj = 0; jj < 8; jj++) BsT[(bnc + jj) * 32 + bkr] = bv[jj];
        __syncthreads();
        bf16x8 af = *(const bf16x8*)&As[(wave * 16 + mr) * 32 + q * 8];
        #pragma unroll
        for (int j = 0; j < 4; j++) {
            bf16x8 bfr = *(const bf16x8*)&BsT[(j * 16 + mr) * 32 + q * 8];
            acc[j] = __builtin_amdgcn_mfma_f32_16x16x32_bf16(af, bfr, acc[j], 0, 0, 0);
        }
    }
    #pragma unroll
    for (int j = 0; j < 4; j++) {
        #pragma unroll
        for (int r = 0; r < 4; r++) {
            int gm = m0 + wave * 16 + q * 4 + r;
            int gn = n0 + j * 16 + mr;
            Cout[(long)bz * sC + (long)gm * N + gn] = f2bf(acc[j][r]);
        }
    }
}

// ---------------- forward norm over L (masked); also wsum = S/(S+eps) ----------------
__global__ void k_fwnorm(const float* __restrict__ z, const int* __restrict__ mask,
                         unsigned short* __restrict__ a_fw, unsigned short* __restrict__ b_fw,
                         float* __restrict__ wsum_a, float* __restrict__ wsum_b)
{
    int be = blockIdx.x;
    int b = be >> 6;
    const float* zr = z + (long)be * L_SZ;
    const int* mr = mask + (long)b * L_SZ;
    int tid = threadIdx.x;
    float sa = 0.f, sb = 0.f;
    for (int l = tid; l < L_SZ; l += 256) {
        float v = zr[l];
        if (mr[l] != 0) { sa += fmaxf(v, 0.f); sb += fmaxf(-v, 0.f); }
    }
    #pragma unroll
    for (int o = 32; o > 0; o >>= 1) { sa += __shfl_down(sa, o); sb += __shfl_down(sb, o); }
    __shared__ float red[8];
    int wave = tid >> 6, lane = tid & 63;
    if (lane == 0) { red[wave] = sa; red[4 + wave] = sb; }
    __syncthreads();
    float ta = red[0] + red[1] + red[2] + red[3];
    float tb = red[4] + red[5] + red[6] + red[7];
    float ia = 1.f / (ta + 1e-9f), ib = 1.f / (tb + 1e-9f);
    if (tid == 0) { wsum_a[be] = ta * ia; wsum_b[be] = tb * ib; }
    for (int l = tid; l < L_SZ; l += 256) {
        float v = zr[l];
        float m = (mr[l] != 0) ? 1.f : 0.f;
        a_fw[(long)be * L_SZ + l] = f2bf(fmaxf(v, 0.f) * m * ia);
        b_fw[(long)be * L_SZ + l] = f2bf(fmaxf(-v, 0.f) * m * ib);
    }
}

// ---------------- backward norm over E (unmasked), f32 out ----------------
__global__ void k_bwnorm(const float* __restrict__ z, float* __restrict__ a_bw, float* __restrict__ b_bw)
{
    int r = blockIdx.x * 256 + threadIdx.x;   // 0 .. B*L-1
    int b = r >> 11, l = r & 2047;
    const float* zb = z + (long)b * NUM_EXP * L_SZ + l;
    float sa = 0.f, sb = 0.f;
    for (int e = 0; e < NUM_EXP; e++) {
        float v = zb[(long)e * L_SZ];
        sa += fmaxf(v, 0.f); sb += fmaxf(-v, 0.f);
    }
    float ia = 1.f / (sa + 1e-9f), ib = 1.f / (sb + 1e-9f);
    float* ar = a_bw + (long)r * NUM_EXP;
    float* br = b_bw + (long)r * NUM_EXP;
    for (int e = 0; e < NUM_EXP; e++) {
        float v = zb[(long)e * L_SZ];
        ar[e] = fmaxf(v, 0.f) * ia;
        br[e] = fmaxf(-v, 0.f) * ib;
    }
}

// ---------------- final: out = sel*(a_bw@cls_a) + (1-sel)*(b_bw@cls_b), f32 ----------------
__launch_bounds__(256)
__global__ void k_final(const float* __restrict__ a_bw, const float* __restrict__ b_bw,
                        const float* __restrict__ cls_a, const float* __restrict__ cls_b,
                        const float* __restrict__ sel, float* __restrict__ out)
{
    __shared__ __align__(16) float Ca[64 * 64];
    __shared__ __align__(16) float Cb[64 * 64];
    __shared__ __align__(16) float Aw[16 * 68];
    __shared__ __align__(16) float Bw[16 * 68];
    const int bz = blockIdx.z;
    const int l0 = blockIdx.y * 16;
    const int d0 = blockIdx.x * 64;
    const int tid = threadIdx.x;
    {
        int er = tid >> 2, dc = (tid & 3) * 16;
        const float* pa = cls_a + ((long)bz * NUM_EXP + er) * D_MODEL + d0 + dc;
        const float* pb = cls_b + ((long)bz * NUM_EXP + er) * D_MODEL + d0 + dc;
        #pragma unroll
        for (int i = 0; i < 16; i += 4) {
            *(float4*)&Ca[er * 64 + dc + i] = *(const float4*)(pa + i);
            *(float4*)&Cb[er * 64 + dc + i] = *(const float4*)(pb + i);
        }
    }
    {
        int li = tid >> 4, ec = (tid & 15) * 4;
        long rrow = (long)bz * L_SZ + l0 + li;
        *(float4*)&Aw[li * 68 + ec] = *(const float4*)(a_bw + rrow * NUM_EXP + ec);
        *(float4*)&Bw[li * 68 + ec] = *(const float4*)(b_bw + rrow * NUM_EXP + ec);
    }
    __syncthreads();
    int li = tid >> 4, dj = tid & 15;
    float aa0=0,aa1=0,aa2=0,aa3=0, ab0=0,ab1=0,ab2=0,ab3=0;
    #pragma unroll 8
    for (int e = 0; e < NUM_EXP; e++) {
        float wa = Aw[li * 68 + e], wb = Bw[li * 68 + e];
        float4 ca = *(float4*)&Ca[e * 64 + dj * 4];
        float4 cb = *(float4*)&Cb[e * 64 + dj * 4];
        aa0 += wa * ca.x; aa1 += wa * ca.y; aa2 += wa * ca.z; aa3 += wa * ca.w;
        ab0 += wb * cb.x; ab1 += wb * cb.y; ab2 += wb * cb.z; ab3 += wb * cb.w;
    }
    long base = ((long)bz * L_SZ + l0 + li) * D_MODEL + d0 + dj * 4;
    float4 s = *(const float4*)(sel + base);
    float4 o;
    o.x = s.x * aa0 + (1.f - s.x) * ab0;
    o.y = s.y * aa1 + (1.f - s.y) * ab1;
    o.z = s.z * aa2 + (1.f - s.z) * ab2;
    o.w = s.w * aa3 + (1.f - s.w) * ab3;
    *(float4*)(out + base) = o;
}

extern "C" void kernel_launch(void* const* d_in, const int* in_sizes, int n_in,
                              void* d_out, int out_size, void* d_ws, size_t ws_size,
                              hipStream_t stream)
{
    const float* x     = (const float*)d_in[0];
    const int*   nidx  = (const int*)d_in[1];
    const int*   mask  = (const int*)d_in[2];
    const float* q_emb = (const float*)d_in[3];
    const float* b_emb = (const float*)d_in[4];
    const float* Wk    = (const float*)d_in[5];
    const float* bk    = (const float*)d_in[6];
    const float* Wa    = (const float*)d_in[7];
    const float* ba    = (const float*)d_in[8];
    const float* Wb    = (const float*)d_in[9];
    const float* bb    = (const float*)d_in[10];
    const float* Ws    = (const float*)d_in[11];
    const float* bs    = (const float*)d_in[12];
    float* out = (float*)d_out;

    constexpr long BLD = (long)B_SZ * L_SZ * D_MODEL;     // 33,554,432
    constexpr long BEL = (long)B_SZ * NUM_EXP * L_SZ;     // 2,097,152
    constexpr long BED = (long)B_SZ * NUM_EXP * D_MODEL;  // 1,048,576
    constexpr long DD  = (long)D_MODEL * D_MODEL;

    char* w = (char*)d_ws;
    size_t off = 0;
    auto carve = [&](size_t bytes) { char* p = w + off; off += (bytes + 255) & ~(size_t)255; return p; };
    unsigned short* x_bf   = (unsigned short*)carve(BLD * 2);
    unsigned short* wk_bf  = (unsigned short*)carve(DD * 2);
    unsigned short* wa_bf  = (unsigned short*)carve(DD * 2);
    unsigned short* wb_bf  = (unsigned short*)carve(DD * 2);
    unsigned short* ws_bf  = (unsigned short*)carve(DD * 2);
    unsigned short* qexp   = (unsigned short*)carve(BED * 2);
    float*          bias_e = (float*)carve(BED * 4);
    float*          qbk    = (float*)carve(B_SZ * NUM_EXP * 4);
    unsigned short* qk     = (unsigned short*)carve(BED * 2);
    float*          z      = (float*)carve(BEL * 4);
    unsigned short* a_fw   = (unsigned short*)carve(BEL * 2);
    unsigned short* b_fw   = (unsigned short*)carve(BEL * 2);
    float*          wsum_a = (float*)carve(B_SZ * NUM_EXP * 4);
    float*          wsum_b = (float*)carve(B_SZ * NUM_EXP * 4);
    float*          a_bw   = (float*)carve(BEL * 4);
    float*          b_bw   = (float*)carve(BEL * 4);
    unsigned short* fwx_a  = (unsigned short*)carve(BED * 2);
    unsigned short* fwx_b  = (unsigned short*)carve(BED * 2);
    float*          cls_a  = (float*)carve(BED * 4);
    float*          cls_b  = (float*)carve(BED * 4);
    if (ws_size < off) return;  // workspace too small: fail cleanly, no corruption
    float* sel = out;           // selector staged in d_out; overwritten in-place by k_final

    // 1. conversions
    k_convert<<<BLD / 2048, 256, 0, stream>>>(x, x_bf, (int)BLD);
    k_convert<<<DD / 2048, 256, 0, stream>>>(Wk, wk_bf, (int)DD);
    k_convert<<<DD / 2048, 256, 0, stream>>>(Wa, wa_bf, (int)DD);
    k_convert<<<DD / 2048, 256, 0, stream>>>(Wb, wb_bf, (int)DD);
    k_convert<<<DD / 2048, 256, 0, stream>>>(Ws, ws_bf, (int)DD);
    k_gather<<<B_SZ * NUM_EXP, 256, 0, stream>>>(nidx, q_emb, b_emb, bk, qexp, bias_e, qbk);

    // 2. qk[b,e,c] = sum_d qexp[b,e,d] * Wk[d,c]           (bn-form, bf16 out)
    k_gemm_bn<<<dim3(16, 1, B_SZ), 256, 0, stream>>>(qexp, wk_bf, qk,
        NUM_EXP, D_MODEL, D_MODEL, (long)NUM_EXP * D_MODEL, 0, (long)NUM_EXP * D_MODEL);

    // 3. z[b,e,l] = (qk[b,e,:] . x[b,l,:] + qbk[b,e]) / 32  (bt-form, f32 out)
    k_gemm_bt<<<dim3(32, 1, B_SZ), 256, 0, stream>>>(qk, x_bf, nullptr, nullptr, qbk, nullptr,
        z, NUM_EXP, L_SZ, D_MODEL, 1.f / 32.f, 0,
        (long)NUM_EXP * D_MODEL, (long)L_SZ * D_MODEL, (long)NUM_EXP * L_SZ);

    // 4. sel = sigmoid(x @ Ws^T + bs)  -> d_out (f32)
    k_gemm_bt<<<dim3(16, 512, 1), 256, 0, stream>>>(x_bf, ws_bf, bs, nullptr, nullptr, nullptr,
        sel, B_SZ * L_SZ, D_MODEL, D_MODEL, 1.f, 2, 0, 0, 0);

    // 5. normalizations
    k_fwnorm<<<B_SZ * NUM_EXP, 256, 0, stream>>>(z, mask, a_fw, b_fw, wsum_a, wsum_b);
    k_bwnorm<<<(B_SZ * L_SZ) / 256, 256, 0, stream>>>(z, a_bw, b_bw);

    // 6. fwx_a[b,e,c] = sum_l a_fw[b,e,l] * x[b,l,c]       (bn-form, bf16 out)
    k_gemm_bn<<<dim3(16, 1, B_SZ), 256, 0, stream>>>(a_fw, x_bf, fwx_a,
        NUM_EXP, D_MODEL, L_SZ, (long)NUM_EXP * L_SZ, (long)L_SZ * D_MODEL, (long)NUM_EXP * D_MODEL);
    k_gemm_bn<<<dim3(16, 1, B_SZ), 256, 0, stream>>>(b_fw, x_bf, fwx_b,
        NUM_EXP, D_MODEL, L_SZ, (long)NUM_EXP * L_SZ, (long)L_SZ * D_MODEL, (long)NUM_EXP * D_MODEL);

    // 7. cls_a[b,e,d] = fwx_a[b,e,:] . Wa[d,:] + wsum_a[b,e]*ba[d] + bias_exp[b,e,d]
    k_gemm_bt<<<dim3(16, 1, B_SZ), 256, 0, stream>>>(fwx_a, wa_bf, ba, wsum_a, nullptr, bias_e,
        cls_a, NUM_EXP, D_MODEL, D_MODEL, 1.f, 0,
        (long)NUM_EXP * D_MODEL, 0, (long)NUM_EXP * D_MODEL);
    k_gemm_bt<<<dim3(16, 1, B_SZ), 256, 0, stream>>>(fwx_b, wb_bf, bb, wsum_b, nullptr, bias_e,
        cls_b, NUM_EXP, D_MODEL, D_MODEL, 1.f, 0,
        (long)NUM_EXP * D_MODEL, 0, (long)NUM_EXP * D_MODEL);

    // 8. final blend (reads sel from d_out, overwrites in place)
    k_final<<<dim3(16, 128, B_SZ), 256, 0, stream>>>(a_bw, b_bw, cls_a, cls_b, sel, out);
}

// Round 2
// 647.623 us; speedup vs baseline: 1.2920x; 1.2920x over previous
//
#include <hip/hip_runtime.h>
#include <math.h>

#define D_MODEL 1024
#define NUM_EXP 64
#define B_SZ 16
#define L_SZ 2048

using bf16x8  = __attribute__((ext_vector_type(8))) __bf16;
using floatx4 = __attribute__((ext_vector_type(4))) float;
using ushort8 = __attribute__((ext_vector_type(8))) unsigned short;
using ushort4v = __attribute__((ext_vector_type(4))) unsigned short;

__device__ __forceinline__ unsigned short f2bf(float f) {
    union { float f; unsigned u; } x; x.f = f;
    unsigned r = (x.u + 0x7fffu + ((x.u >> 16) & 1u)) >> 16;
    return (unsigned short)r;
}
__device__ __forceinline__ float bf2f(unsigned short h) {
    union { unsigned u; float f; } x; x.u = ((unsigned)h) << 16;
    return x.f;
}

// async 16B global->LDS (lds base must be wave-uniform; lane i lands at base+16*i)
#define GLD16(gp, lp) __builtin_amdgcn_global_load_lds( \
    (const __attribute__((address_space(1))) unsigned int*)(gp), \
    (__attribute__((address_space(3))) unsigned int*)(lp), 16, 0, 0)

// ---------------- f32 -> bf16 convert ----------------
__global__ void k_convert(const float* __restrict__ in, unsigned short* __restrict__ out, int n) {
    int i = (blockIdx.x * blockDim.x + threadIdx.x) * 8;
    if (i >= n) return;
    float4 a = *(const float4*)(in + i);
    float4 b = *(const float4*)(in + i + 4);
    ushort8 r;
    r[0]=f2bf(a.x); r[1]=f2bf(a.y); r[2]=f2bf(a.z); r[3]=f2bf(a.w);
    r[4]=f2bf(b.x); r[5]=f2bf(b.y); r[6]=f2bf(b.z); r[7]=f2bf(b.w);
    *(ushort8*)(out + i) = r;
}

// ---------------- gather q_emb/b_emb rows; qbk[be] = q_row . bk ----------------
__global__ void k_gather(const int* __restrict__ idx, const float* __restrict__ q_emb,
                         const float* __restrict__ b_emb, const float* __restrict__ bk,
                         unsigned short* __restrict__ qexp, float* __restrict__ bias_exp,
                         float* __restrict__ qbk)
{
    int be = blockIdx.x;
    int row = idx[be];
    int t = threadIdx.x;
    const float* qs = q_emb + (long)row * D_MODEL;
    const float* bsrc = b_emb + (long)row * D_MODEL;
    float4 q4 = *(const float4*)(qs + t * 4);
    float4 k4 = *(const float4*)(bk + t * 4);
    float4 b4 = *(const float4*)(bsrc + t * 4);
    ushort4v r; r[0]=f2bf(q4.x); r[1]=f2bf(q4.y); r[2]=f2bf(q4.z); r[3]=f2bf(q4.w);
    *(ushort4v*)(qexp + (long)be * D_MODEL + t * 4) = r;
    *(float4*)(bias_exp + (long)be * D_MODEL + t * 4) = b4;
    float p = q4.x*k4.x + q4.y*k4.y + q4.z*k4.z + q4.w*k4.w;
    #pragma unroll
    for (int o = 32; o > 0; o >>= 1) p += __shfl_down(p, o);
    __shared__ float red[4];
    if ((t & 63) == 0) red[t >> 6] = p;
    __syncthreads();
    if (t == 0) qbk[be] = red[0] + red[1] + red[2] + red[3];
}

// ---------------- GEMM, B^T layout: C = epi( (A[M,K] @ B[N,K]^T) ) ----------------
// v = (acc + rowbias[gm]) * scale + colbias[gn]*(roww?roww[gm]:1) + biasMat[gm,gn]
// flags: bit0 = store bf16, bit1 = sigmoid, bit2 = split hi/lo bf16 TRANSPOSED store
__launch_bounds__(256)
__global__ void k_gemm_bt(const unsigned short* __restrict__ A,
                          const unsigned short* __restrict__ Bm,
                          const float* __restrict__ colbias,
                          const float* __restrict__ roww,
                          const float* __restrict__ rowbias,
                          const float* __restrict__ biasMat,
                          void* __restrict__ Cout,
                          unsigned short* __restrict__ Cout2,
                          int M, int N, int K, float scale, int flags,
                          long sA, long sB, long sC)
{
    __shared__ __align__(16) unsigned short As[64 * 32];
    __shared__ __align__(16) unsigned short Bs[64 * 32];
    const int bz = blockIdx.z;
    const unsigned short* Ab = A + (long)bz * sA;
    const unsigned short* Bb = Bm + (long)bz * sB;
    const int tid = threadIdx.x;
    const int wave = tid >> 6, lane = tid & 63;
    const int m0 = blockIdx.y * 64, n0 = blockIdx.x * 64;
    const int lrow = tid >> 2, lk = (tid & 3) * 8;
    const int q = lane >> 4, mr = lane & 15;

    floatx4 acc[4];
    floatx4 z4 = {0.f, 0.f, 0.f, 0.f};
    #pragma unroll
    for (int j = 0; j < 4; j++) acc[j] = z4;

    const unsigned short* Aptr = Ab + (long)(m0 + lrow) * K + lk;
    const unsigned short* Bptr = Bb + (long)(n0 + lrow) * K + lk;

    for (int k0 = 0; k0 < K; k0 += 32) {
        __syncthreads();
        *(ushort8*)&As[lrow * 32 + lk] = *(const ushort8*)(Aptr + k0);
        *(ushort8*)&Bs[lrow * 32 + lk] = *(const ushort8*)(Bptr + k0);
        __syncthreads();
        bf16x8 af = *(const bf16x8*)&As[(wave * 16 + mr) * 32 + q * 8];
        #pragma unroll
        for (int j = 0; j < 4; j++) {
            bf16x8 bfr = *(const bf16x8*)&Bs[(j * 16 + mr) * 32 + q * 8];
            acc[j] = __builtin_amdgcn_mfma_f32_16x16x32_bf16(af, bfr, acc[j], 0, 0, 0);
        }
    }
    #pragma unroll
    for (int j = 0; j < 4; j++) {
        int gn = n0 + j * 16 + mr;
        float cb = colbias ? colbias[gn] : 0.f;
        #pragma unroll
        for (int r = 0; r < 4; r++) {
            int gm = m0 + wave * 16 + q * 4 + r;
            float v = acc[j][r];
            if (rowbias) v += rowbias[(long)bz * M + gm];
            v *= scale;
            if (colbias) v += roww ? cb * roww[(long)bz * M + gm] : cb;
            if (biasMat) v += biasMat[((long)bz * M + gm) * (long)N + gn];
            if (flags & 2) v = 1.f / (1.f + __expf(-v));
            if (flags & 4) {
                // transposed split store: [n, m]
                long tix = (long)bz * sC + (long)gn * M + gm;
                unsigned short hi = f2bf(v);
                ((unsigned short*)Cout)[tix] = hi;
                Cout2[tix] = f2bf(v - bf2f(hi));
            } else {
                long cidx = (long)bz * sC + (long)gm * N + gn;
                if (flags & 1) ((unsigned short*)Cout)[cidx] = f2bf(v);
                else           ((float*)Cout)[cidx] = v;
            }
        }
    }
}

// ---------------- GEMM, normal-B layout: C_bf16 = A[M,K] @ B[K,N] ----------------
__launch_bounds__(256)
__global__ void k_gemm_bn(const unsigned short* __restrict__ A,
                          const unsigned short* __restrict__ Bm,
                          unsigned short* __restrict__ Cout,
                          int M, int N, int K,
                          long sA, long sB, long sC)
{
    __shared__ __align__(16) unsigned short As[64 * 32];
    __shared__ __align__(16) unsigned short BsT[64 * 32];
    const int bz = blockIdx.z;
    const unsigned short* Ab = A + (long)bz * sA;
    const unsigned short* Bb = Bm + (long)bz * sB;
    const int tid = threadIdx.x;
    const int wave = tid >> 6, lane = tid & 63;
    const int m0 = blockIdx.y * 64, n0 = blockIdx.x * 64;
    const int lrow = tid >> 2, lk = (tid & 3) * 8;
    const int bkr = tid >> 3, bnc = (tid & 7) * 8;
    const int q = lane >> 4, mr = lane & 15;

    floatx4 acc[4];
    floatx4 z4 = {0.f, 0.f, 0.f, 0.f};
    #pragma unroll
    for (int j = 0; j < 4; j++) acc[j] = z4;

    for (int k0 = 0; k0 < K; k0 += 32) {
        __syncthreads();
        *(ushort8*)&As[lrow * 32 + lk] = *(const ushort8*)(Ab + (long)(m0 + lrow) * K + k0 + lk);
        ushort8 bv = *(const ushort8*)(Bb + (long)(k0 + bkr) * N + n0 + bnc);
        #pragma unroll
        for (int jj = 0; jj < 8; jj++) BsT[(bnc + jj) * 32 + bkr] = bv[jj];
        __syncthreads();
        bf16x8 af = *(const bf16x8*)&As[(wave * 16 + mr) * 32 + q * 8];
        #pragma unroll
        for (int j = 0; j < 4; j++) {
            bf16x8 bfr = *(const bf16x8*)&BsT[(j * 16 + mr) * 32 + q * 8];
            acc[j] = __builtin_amdgcn_mfma_f32_16x16x32_bf16(af, bfr, acc[j], 0, 0, 0);
        }
    }
    #pragma unroll
    for (int j = 0; j < 4; j++) {
        #pragma unroll
        for (int r = 0; r < 4; r++) {
            int gm = m0 + wave * 16 + q * 4 + r;
            int gn = n0 + j * 16 + mr;
            Cout[(long)bz * sC + (long)gm * N + gn] = f2bf(acc[j][r]);
        }
    }
}

// ---------------- selector GEMM: 128x128 tile, BK=32, global_load_lds + XOR swizzle ----------------
// C[m,n] = sigmoid( A[m,:]·B[n,:] + bias[n] ), M=32768, N=K=1024
__launch_bounds__(256)
__global__ void k_gemm_sel(const unsigned short* __restrict__ A,
                           const unsigned short* __restrict__ Bm,
                           const float* __restrict__ bias,
                           float* __restrict__ C)
{
    __shared__ __align__(16) unsigned short As[128 * 32];
    __shared__ __align__(16) unsigned short Bs[128 * 32];
    const int tid = threadIdx.x;
    const int wave = tid >> 6, lane = tid & 63;
    const int q = lane >> 4, mr = lane & 15;
    const int wm = wave & 1, wn = wave >> 1;
    const int m0 = blockIdx.y * 128, n0 = blockIdx.x * 128;

    // staging chunk assignment: chunk slot s -> row=s>>2, swizzled kc' = s&3,
    // holds global kc = kc' ^ ((row>>1)&3)
    int rows[2], kofs8[2];
    #pragma unroll
    for (int c = 0; c < 2; c++) {
        int s = c * 256 + tid;
        int row = s >> 2;
        rows[c] = row;
        kofs8[c] = ((s & 3) ^ ((row >> 1) & 3)) * 8;
    }
    const unsigned short* gA0 = A + (long)(m0 + rows[0]) * 1024 + kofs8[0];
    const unsigned short* gA1 = A + (long)(m0 + rows[1]) * 1024 + kofs8[1];
    const unsigned short* gB0 = Bm + (long)(n0 + rows[0]) * 1024 + kofs8[0];
    const unsigned short* gB1 = Bm + (long)(n0 + rows[1]) * 1024 + kofs8[1];
    unsigned short* LA0 = &As[(0 * 256 + wave * 64) * 8];
    unsigned short* LA1 = &As[(1 * 256 + wave * 64) * 8];
    unsigned short* LB0 = &Bs[(0 * 256 + wave * 64) * 8];
    unsigned short* LB1 = &Bs[(1 * 256 + wave * 64) * 8];

    floatx4 acc[4][4];
    floatx4 z4 = {0.f, 0.f, 0.f, 0.f};
    #pragma unroll
    for (int i = 0; i < 4; i++)
        #pragma unroll
        for (int j = 0; j < 4; j++) acc[i][j] = z4;

    const int kread = (q ^ ((mr >> 1) & 3)) * 8;   // swizzled fragment k-offset

    for (int k0 = 0; k0 < 1024; k0 += 32) {
        __syncthreads();
        GLD16(gA0 + k0, LA0);
        GLD16(gA1 + k0, LA1);
        GLD16(gB0 + k0, LB0);
        GLD16(gB1 + k0, LB1);
        __syncthreads();
        bf16x8 af[4], bfv[4];
        #pragma unroll
        for (int i = 0; i < 4; i++)
            af[i] = *(const bf16x8*)&As[(wm * 64 + i * 16 + mr) * 32 + kread];
        #pragma unroll
        for (int j = 0; j < 4; j++)
            bfv[j] = *(const bf16x8*)&Bs[(wn * 64 + j * 16 + mr) * 32 + kread];
        #pragma unroll
        for (int i = 0; i < 4; i++)
            #pragma unroll
            for (int j = 0; j < 4; j++)
                acc[i][j] = __builtin_amdgcn_mfma_f32_16x16x32_bf16(af[i], bfv[j], acc[i][j], 0, 0, 0);
    }

    #pragma unroll
    for (int i = 0; i < 4; i++) {
        #pragma unroll
        for (int j = 0; j < 4; j++) {
            int gn = n0 + wn * 64 + j * 16 + mr;
            float cb = bias[gn];
            #pragma unroll
            for (int r = 0; r < 4; r++) {
                int gm = m0 + wm * 64 + i * 16 + q * 4 + r;
                float v = acc[i][j][r] + cb;
                v = 1.f / (1.f + __expf(-v));
                C[(long)gm * 1024 + gn] = v;
            }
        }
    }
}

// ---------------- forward norm over L (masked); also wsum = S/(S+eps) ----------------
__global__ void k_fwnorm(const float* __restrict__ z, const int* __restrict__ mask,
                         unsigned short* __restrict__ a_fw, unsigned short* __restrict__ b_fw,
                         float* __restrict__ wsum_a, float* __restrict__ wsum_b)
{
    int be = blockIdx.x;
    int b = be >> 6;
    const float* zr = z + (long)be * L_SZ;
    const int* mr = mask + (long)b * L_SZ;
    int tid = threadIdx.x;
    float sa = 0.f, sb = 0.f;
    for (int l = tid; l < L_SZ; l += 256) {
        float v = zr[l];
        if (mr[l] != 0) { sa += fmaxf(v, 0.f); sb += fmaxf(-v, 0.f); }
    }
    #pragma unroll
    for (int o = 32; o > 0; o >>= 1) { sa += __shfl_down(sa, o); sb += __shfl_down(sb, o); }
    __shared__ float red[8];
    int wave = tid >> 6, lane = tid & 63;
    if (lane == 0) { red[wave] = sa; red[4 + wave] = sb; }
    __syncthreads();
    float ta = red[0] + red[1] + red[2] + red[3];
    float tb = red[4] + red[5] + red[6] + red[7];
    float ia = 1.f / (ta + 1e-9f), ib = 1.f / (tb + 1e-9f);
    if (tid == 0) { wsum_a[be] = ta * ia; wsum_b[be] = tb * ib; }
    for (int l = tid; l < L_SZ; l += 256) {
        float v = zr[l];
        float m = (mr[l] != 0) ? 1.f : 0.f;
        a_fw[(long)be * L_SZ + l] = f2bf(fmaxf(v, 0.f) * m * ia);
        b_fw[(long)be * L_SZ + l] = f2bf(fmaxf(-v, 0.f) * m * ib);
    }
}

// ---------------- backward norm over E (unmasked), bf16 out ----------------
__global__ void k_bwnorm(const float* __restrict__ z, unsigned short* __restrict__ a_bw,
                         unsigned short* __restrict__ b_bw)
{
    int r = blockIdx.x * 256 + threadIdx.x;   // 0 .. B*L-1
    int b = r >> 11, l = r & 2047;
    const float* zb = z + (long)b * NUM_EXP * L_SZ + l;
    float sa = 0.f, sb = 0.f;
    float va[NUM_EXP];
    #pragma unroll 8
    for (int e = 0; e < NUM_EXP; e++) {
        float v = zb[(long)e * L_SZ];
        va[e] = v;
        sa += fmaxf(v, 0.f); sb += fmaxf(-v, 0.f);
    }
    float ia = 1.f / (sa + 1e-9f), ib = 1.f / (sb + 1e-9f);
    unsigned short* ar = a_bw + (long)r * NUM_EXP;
    unsigned short* br = b_bw + (long)r * NUM_EXP;
    #pragma unroll 8
    for (int e = 0; e < NUM_EXP; e++) {
        float v = va[e];
        ar[e] = f2bf(fmaxf(v, 0.f) * ia);
        br[e] = f2bf(fmaxf(-v, 0.f) * ib);
    }
}

// ---------------- final: out = sel*(aw@clsA) + (1-sel)*(bw@clsB) via MFMA ----------------
// cls tensors pre-transposed [d,e] and split hi/lo bf16.
__launch_bounds__(256)
__global__ void k_final_mfma(const unsigned short* __restrict__ aw,   // [B,L,E] bf16
                             const unsigned short* __restrict__ bw,
                             const unsigned short* __restrict__ caHi, // [B,D,E] bf16
                             const unsigned short* __restrict__ caLo,
                             const unsigned short* __restrict__ cbHi,
                             const unsigned short* __restrict__ cbLo,
                             const float* __restrict__ sel,
                             float* __restrict__ out)
{
    // stride 72 ushort: 16B-aligned rows, 2-way max bank aliasing (free)
    __shared__ __align__(16) unsigned short Aa[64 * 72];
    __shared__ __align__(16) unsigned short Ab[64 * 72];
    __shared__ __align__(16) unsigned short BaH[64 * 72];
    __shared__ __align__(16) unsigned short BaL[64 * 72];
    __shared__ __align__(16) unsigned short BbH[64 * 72];
    __shared__ __align__(16) unsigned short BbL[64 * 72];
    const int bz = blockIdx.z;
    const int l0 = blockIdx.y * 64, d0 = blockIdx.x * 64;
    const int tid = threadIdx.x;
    const int wave = tid >> 6, lane = tid & 63;
    const int q = lane >> 4, mr = lane & 15;

    const unsigned short* awb = aw + ((long)bz * L_SZ + l0) * NUM_EXP;
    const unsigned short* bwb = bw + ((long)bz * L_SZ + l0) * NUM_EXP;
    const long cbase = ((long)bz * D_MODEL + d0) * NUM_EXP;

    #pragma unroll
    for (int c = 0; c < 2; c++) {
        int idx = c * 256 + tid;
        int row = idx >> 3, kc = (idx & 7) * 8;
        int lw = row * 72 + kc;
        long ga = (long)row * NUM_EXP + kc;
        *(ushort8*)&Aa[lw]  = *(const ushort8*)(awb + ga);
        *(ushort8*)&Ab[lw]  = *(const ushort8*)(bwb + ga);
        *(ushort8*)&BaH[lw] = *(const ushort8*)(caHi + cbase + ga);
        *(ushort8*)&BaL[lw] = *(const ushort8*)(caLo + cbase + ga);
        *(ushort8*)&BbH[lw] = *(const ushort8*)(cbHi + cbase + ga);
        *(ushort8*)&BbL[lw] = *(const ushort8*)(cbLo + cbase + ga);
    }
    __syncthreads();

    floatx4 accA[4], accB[4];
    floatx4 z4 = {0.f, 0.f, 0.f, 0.f};
    #pragma unroll
    for (int j = 0; j < 4; j++) { accA[j] = z4; accB[j] = z4; }

    #pragma unroll
    for (int ks = 0; ks < 2; ks++) {
        int ko = ks * 32 + q * 8;
        bf16x8 fa = *(const bf16x8*)&Aa[(wave * 16 + mr) * 72 + ko];
        bf16x8 fb = *(const bf16x8*)&Ab[(wave * 16 + mr) * 72 + ko];
        #pragma unroll
        for (int j = 0; j < 4; j++) {
            int bo = (j * 16 + mr) * 72 + ko;
            accA[j] = __builtin_amdgcn_mfma_f32_16x16x32_bf16(fa, *(const bf16x8*)&BaH[bo], accA[j], 0, 0, 0);
            accA[j] = __builtin_amdgcn_mfma_f32_16x16x32_bf16(fa, *(const bf16x8*)&BaL[bo], accA[j], 0, 0, 0);
            accB[j] = __builtin_amdgcn_mfma_f32_16x16x32_bf16(fb, *(const bf16x8*)&BbH[bo], accB[j], 0, 0, 0);
            accB[j] = __builtin_amdgcn_mfma_f32_16x16x32_bf16(fb, *(const bf16x8*)&BbL[bo], accB[j], 0, 0, 0);
        }
    }

    #pragma unroll
    for (int j = 0; j < 4; j++) {
        #pragma unroll
        for (int r = 0; r < 4; r++) {
            int gl = l0 + wave * 16 + q * 4 + r;
            int gd = d0 + j * 16 + mr;
            long o = ((long)bz * L_SZ + gl) * D_MODEL + gd;
            float s = sel[o];
            out[o] = s * accA[j][r] + (1.f - s) * accB[j][r];
        }
    }
}

extern "C" void kernel_launch(void* const* d_in, const int* in_sizes, int n_in,
                              void* d_out, int out_size, void* d_ws, size_t ws_size,
                              hipStream_t stream)
{
    const float* x     = (const float*)d_in[0];
    const int*   nidx  = (const int*)d_in[1];
    const int*   mask  = (const int*)d_in[2];
    const float* q_emb = (const float*)d_in[3];
    const float* b_emb = (const float*)d_in[4];
    const float* Wk    = (const float*)d_in[5];
    const float* bk    = (const float*)d_in[6];
    const float* Wa    = (const float*)d_in[7];
    const float* ba    = (const float*)d_in[8];
    const float* Wb    = (const float*)d_in[9];
    const float* bb    = (const float*)d_in[10];
    const float* Ws    = (const float*)d_in[11];
    const float* bs    = (const float*)d_in[12];
    float* out = (float*)d_out;

    constexpr long BLD = (long)B_SZ * L_SZ * D_MODEL;
    constexpr long BEL = (long)B_SZ * NUM_EXP * L_SZ;
    constexpr long BED = (long)B_SZ * NUM_EXP * D_MODEL;
    constexpr long DD  = (long)D_MODEL * D_MODEL;

    char* w = (char*)d_ws;
    size_t off = 0;
    auto carve = [&](size_t bytes) { char* p = w + off; off += (bytes + 255) & ~(size_t)255; return p; };
    unsigned short* x_bf   = (unsigned short*)carve(BLD * 2);
    unsigned short* wk_bf  = (unsigned short*)carve(DD * 2);
    unsigned short* wa_bf  = (unsigned short*)carve(DD * 2);
    unsigned short* wb_bf  = (unsigned short*)carve(DD * 2);
    unsigned short* ws_bf  = (unsigned short*)carve(DD * 2);
    unsigned short* qexp   = (unsigned short*)carve(BED * 2);
    float*          bias_e = (float*)carve(BED * 4);
    float*          qbk    = (float*)carve(B_SZ * NUM_EXP * 4);
    unsigned short* qk     = (unsigned short*)carve(BED * 2);
    float*          z      = (float*)carve(BEL * 4);
    unsigned short* a_fw   = (unsigned short*)carve(BEL * 2);
    unsigned short* b_fw   = (unsigned short*)carve(BEL * 2);
    float*          wsum_a = (float*)carve(B_SZ * NUM_EXP * 4);
    float*          wsum_b = (float*)carve(B_SZ * NUM_EXP * 4);
    unsigned short* a_bw   = (unsigned short*)carve(BEL * 2);
    unsigned short* b_bw   = (unsigned short*)carve(BEL * 2);
    unsigned short* fwx_a  = (unsigned short*)carve(BED * 2);
    unsigned short* fwx_b  = (unsigned short*)carve(BED * 2);
    unsigned short* caHi   = (unsigned short*)carve(BED * 2);   // [B,D,E] transposed
    unsigned short* caLo   = (unsigned short*)carve(BED * 2);
    unsigned short* cbHi   = (unsigned short*)carve(BED * 2);
    unsigned short* cbLo   = (unsigned short*)carve(BED * 2);
    if (ws_size < off) return;
    float* sel = out;   // selector staged in d_out; k_final_mfma overwrites in place

    // 1. conversions
    k_convert<<<BLD / 2048, 256, 0, stream>>>(x, x_bf, (int)BLD);
    k_convert<<<DD / 2048, 256, 0, stream>>>(Wk, wk_bf, (int)DD);
    k_convert<<<DD / 2048, 256, 0, stream>>>(Wa, wa_bf, (int)DD);
    k_convert<<<DD / 2048, 256, 0, stream>>>(Wb, wb_bf, (int)DD);
    k_convert<<<DD / 2048, 256, 0, stream>>>(Ws, ws_bf, (int)DD);
    k_gather<<<B_SZ * NUM_EXP, 256, 0, stream>>>(nidx, q_emb, b_emb, bk, qexp, bias_e, qbk);

    // 2. qk[b,e,c] = sum_d qexp[b,e,d] * Wk[d,c]
    k_gemm_bn<<<dim3(16, 1, B_SZ), 256, 0, stream>>>(qexp, wk_bf, qk,
        NUM_EXP, D_MODEL, D_MODEL, (long)NUM_EXP * D_MODEL, 0, (long)NUM_EXP * D_MODEL);

    // 3. z[b,e,l] = (qk[b,e,:] . x[b,l,:] + qbk[b,e]) / 32
    k_gemm_bt<<<dim3(32, 1, B_SZ), 256, 0, stream>>>(qk, x_bf, nullptr, nullptr, qbk, nullptr,
        z, nullptr, NUM_EXP, L_SZ, D_MODEL, 1.f / 32.f, 0,
        (long)NUM_EXP * D_MODEL, (long)L_SZ * D_MODEL, (long)NUM_EXP * L_SZ);

    // 4. sel = sigmoid(x @ Ws^T + bs)  -> d_out (f32), 128-tile async-staged GEMM
    k_gemm_sel<<<dim3(8, 256, 1), 256, 0, stream>>>(x_bf, ws_bf, bs, sel);

    // 5. normalizations
    k_fwnorm<<<B_SZ * NUM_EXP, 256, 0, stream>>>(z, mask, a_fw, b_fw, wsum_a, wsum_b);
    k_bwnorm<<<(B_SZ * L_SZ) / 256, 256, 0, stream>>>(z, a_bw, b_bw);

    // 6. fwx_a[b,e,c] = sum_l a_fw[b,e,l] * x[b,l,c]
    k_gemm_bn<<<dim3(16, 1, B_SZ), 256, 0, stream>>>(a_fw, x_bf, fwx_a,
        NUM_EXP, D_MODEL, L_SZ, (long)NUM_EXP * L_SZ, (long)L_SZ * D_MODEL, (long)NUM_EXP * D_MODEL);
    k_gemm_bn<<<dim3(16, 1, B_SZ), 256, 0, stream>>>(b_fw, x_bf, fwx_b,
        NUM_EXP, L_SZ == L_SZ ? D_MODEL : D_MODEL, L_SZ, (long)NUM_EXP * L_SZ, (long)L_SZ * D_MODEL, (long)NUM_EXP * D_MODEL);

    // 7. cls[b,e,d] = fwx[b,e,:] . W[d,:] + wsum[b,e]*bias[d] + bias_exp[b,e,d]
    //    stored transposed [d,e], split bf16 hi/lo (flags=4)
    k_gemm_bt<<<dim3(16, 1, B_SZ), 256, 0, stream>>>(fwx_a, wa_bf, ba, wsum_a, nullptr, bias_e,
        caHi, caLo, NUM_EXP, D_MODEL, D_MODEL, 1.f, 4,
        (long)NUM_EXP * D_MODEL, 0, (long)NUM_EXP * D_MODEL);
    k_gemm_bt<<<dim3(16, 1, B_SZ), 256, 0, stream>>>(fwx_b, wb_bf, bb, wsum_b, nullptr, bias_e,
        cbHi, cbLo, NUM_EXP, D_MODEL, D_MODEL, 1.f, 4,
        (long)NUM_EXP * D_MODEL, 0, (long)NUM_EXP * D_MODEL);

    // 8. final blend via MFMA (reads sel from d_out, overwrites in place)
    k_final_mfma<<<dim3(16, 32, B_SZ), 256, 0, stream>>>(a_bw, b_bw, caHi, caLo, cbHi, cbLo, sel, out);
}

// Round 3
// 553.682 us; speedup vs baseline: 1.5112x; 1.1697x over previous
//
#include <hip/hip_runtime.h>
#include <math.h>

#define D_MODEL 1024
#define NUM_EXP 64
#define B_SZ 16
#define L_SZ 2048

using bf16x8  = __attribute__((ext_vector_type(8))) __bf16;
using floatx4 = __attribute__((ext_vector_type(4))) float;
using ushort8 = __attribute__((ext_vector_type(8))) unsigned short;
using ushort4v = __attribute__((ext_vector_type(4))) unsigned short;

__device__ __forceinline__ unsigned short f2bf(float f) {
    union { float f; unsigned u; } x; x.f = f;
    unsigned r = (x.u + 0x7fffu + ((x.u >> 16) & 1u)) >> 16;
    return (unsigned short)r;
}
__device__ __forceinline__ float bf2f(unsigned short h) {
    union { unsigned u; float f; } x; x.u = ((unsigned)h) << 16;
    return x.f;
}

// async 16B global->LDS (lds base wave-uniform; lane i lands at base+16*i)
#define GLD16(gp, lp) __builtin_amdgcn_global_load_lds( \
    (const __attribute__((address_space(1))) unsigned int*)(gp), \
    (__attribute__((address_space(3))) unsigned int*)(lp), 16, 0, 0)

// ---------------- x: f32 -> bf16, both [B,L,D] and transposed [B,D,L] ----------------
__global__ void k_convx(const float* __restrict__ in, unsigned short* __restrict__ outN,
                        unsigned short* __restrict__ outT)
{
    __shared__ unsigned short T[64][65];
    const int b = blockIdx.z;
    const int l0 = blockIdx.y * 64, c0 = blockIdx.x * 64;
    const int t = threadIdx.x;
    const int tr = t >> 4, tc = (t & 15) * 4;
    const float* src = in + ((long)b * L_SZ + l0) * D_MODEL + c0;
    unsigned short* dN = outN + ((long)b * L_SZ + l0) * D_MODEL + c0;
    #pragma unroll
    for (int i = 0; i < 4; i++) {
        int r = tr + i * 16;
        float4 v = *(const float4*)(src + (long)r * D_MODEL + tc);
        ushort4v u; u[0]=f2bf(v.x); u[1]=f2bf(v.y); u[2]=f2bf(v.z); u[3]=f2bf(v.w);
        *(ushort4v*)(dN + (long)r * D_MODEL + tc) = u;
        T[r][tc+0]=u[0]; T[r][tc+1]=u[1]; T[r][tc+2]=u[2]; T[r][tc+3]=u[3];
    }
    __syncthreads();
    unsigned short* dT = outT + ((long)b * D_MODEL + c0) * L_SZ + l0;
    #pragma unroll
    for (int i = 0; i < 4; i++) {
        int c = tr + i * 16;
        ushort4v u;
        u[0]=T[tc+0][c]; u[1]=T[tc+1][c]; u[2]=T[tc+2][c]; u[3]=T[tc+3][c];
        *(ushort4v*)(dT + (long)c * L_SZ + tc) = u;
    }
}

// ---------------- Wk: f32 [K,N] -> bf16 transposed [N,K] ----------------
__global__ void k_transw(const float* __restrict__ in, unsigned short* __restrict__ outT)
{
    __shared__ unsigned short T[64][65];
    const int r0 = blockIdx.y * 64, c0 = blockIdx.x * 64;
    const int t = threadIdx.x;
    const int tr = t >> 4, tc = (t & 15) * 4;
    const float* src = in + (long)r0 * D_MODEL + c0;
    #pragma unroll
    for (int i = 0; i < 4; i++) {
        int r = tr + i * 16;
        float4 v = *(const float4*)(src + (long)r * D_MODEL + tc);
        T[r][tc+0]=f2bf(v.x); T[r][tc+1]=f2bf(v.y); T[r][tc+2]=f2bf(v.z); T[r][tc+3]=f2bf(v.w);
    }
    __syncthreads();
    unsigned short* dT = outT + ((long)c0) * D_MODEL + r0;
    #pragma unroll
    for (int i = 0; i < 4; i++) {
        int c = tr + i * 16;
        ushort4v u;
        u[0]=T[tc+0][c]; u[1]=T[tc+1][c]; u[2]=T[tc+2][c]; u[3]=T[tc+3][c];
        *(ushort4v*)(dT + (long)c * D_MODEL + tc) = u;
    }
}

// ---------------- Wa/Wb/Ws straight f32->bf16 (merged) ----------------
__global__ void k_convert3(const float* __restrict__ a, const float* __restrict__ b,
                           const float* __restrict__ c,
                           unsigned short* __restrict__ oa, unsigned short* __restrict__ ob,
                           unsigned short* __restrict__ oc)
{
    long i = ((long)blockIdx.x * 256 + threadIdx.x) * 8;
    int which = (int)(i >> 20);
    long off = i & ((1L << 20) - 1);
    const float* src = which == 0 ? a : which == 1 ? b : c;
    unsigned short* dst = which == 0 ? oa : which == 1 ? ob : oc;
    float4 v0 = *(const float4*)(src + off);
    float4 v1 = *(const float4*)(src + off + 4);
    ushort8 r;
    r[0]=f2bf(v0.x); r[1]=f2bf(v0.y); r[2]=f2bf(v0.z); r[3]=f2bf(v0.w);
    r[4]=f2bf(v1.x); r[5]=f2bf(v1.y); r[6]=f2bf(v1.z); r[7]=f2bf(v1.w);
    *(ushort8*)(dst + off) = r;
}

// ---------------- gather q_emb/b_emb rows; qbk[be] = q_row . bk ----------------
__global__ void k_gather(const int* __restrict__ idx, const float* __restrict__ q_emb,
                         const float* __restrict__ b_emb, const float* __restrict__ bk,
                         unsigned short* __restrict__ qexp, float* __restrict__ bias_exp,
                         float* __restrict__ qbk)
{
    int be = blockIdx.x;
    int row = idx[be];
    int t = threadIdx.x;
    const float* qs = q_emb + (long)row * D_MODEL;
    const float* bsrc = b_emb + (long)row * D_MODEL;
    float4 q4 = *(const float4*)(qs + t * 4);
    float4 k4 = *(const float4*)(bk + t * 4);
    float4 b4 = *(const float4*)(bsrc + t * 4);
    ushort4v r; r[0]=f2bf(q4.x); r[1]=f2bf(q4.y); r[2]=f2bf(q4.z); r[3]=f2bf(q4.w);
    *(ushort4v*)(qexp + (long)be * D_MODEL + t * 4) = r;
    *(float4*)(bias_exp + (long)be * D_MODEL + t * 4) = b4;
    float p = q4.x*k4.x + q4.y*k4.y + q4.z*k4.z + q4.w*k4.w;
    #pragma unroll
    for (int o = 32; o > 0; o >>= 1) p += __shfl_down(p, o);
    __shared__ float red[4];
    if ((t & 63) == 0) red[t >> 6] = p;
    __syncthreads();
    if (t == 0) qbk[be] = red[0] + red[1] + red[2] + red[3];
}

// ---------------- generic bt GEMM: C = epi(A[M,K] @ B[N,K]^T) ----------------
// v = (acc + rowbias[gm]) * scale ; flags: bit0 = bf16 store (else f32)
__launch_bounds__(256)
__global__ void k_gemm_bt(const unsigned short* __restrict__ A,
                          const unsigned short* __restrict__ Bm,
                          const float* __restrict__ rowbias,
                          void* __restrict__ Cout,
                          int M, int N, int K, float scale, int flags,
                          long sA, long sB, long sC)
{
    __shared__ __align__(16) unsigned short As[64 * 32];
    __shared__ __align__(16) unsigned short Bs[64 * 32];
    const int bz = blockIdx.z;
    const unsigned short* Ab = A + (long)bz * sA;
    const unsigned short* Bb = Bm + (long)bz * sB;
    const int tid = threadIdx.x;
    const int wave = tid >> 6, lane = tid & 63;
    const int m0 = blockIdx.y * 64, n0 = blockIdx.x * 64;
    const int lrow = tid >> 2, lk = (tid & 3) * 8;
    const int q = lane >> 4, mr = lane & 15;

    floatx4 acc[4];
    floatx4 z4 = {0.f, 0.f, 0.f, 0.f};
    #pragma unroll
    for (int j = 0; j < 4; j++) acc[j] = z4;

    const unsigned short* Aptr = Ab + (long)(m0 + lrow) * K + lk;
    const unsigned short* Bptr = Bb + (long)(n0 + lrow) * K + lk;

    for (int k0 = 0; k0 < K; k0 += 32) {
        __syncthreads();
        *(ushort8*)&As[lrow * 32 + lk] = *(const ushort8*)(Aptr + k0);
        *(ushort8*)&Bs[lrow * 32 + lk] = *(const ushort8*)(Bptr + k0);
        __syncthreads();
        bf16x8 af = *(const bf16x8*)&As[(wave * 16 + mr) * 32 + q * 8];
        #pragma unroll
        for (int j = 0; j < 4; j++) {
            bf16x8 bfr = *(const bf16x8*)&Bs[(j * 16 + mr) * 32 + q * 8];
            acc[j] = __builtin_amdgcn_mfma_f32_16x16x32_bf16(af, bfr, acc[j], 0, 0, 0);
        }
    }
    #pragma unroll
    for (int j = 0; j < 4; j++) {
        int gn = n0 + j * 16 + mr;
        #pragma unroll
        for (int r = 0; r < 4; r++) {
            int gm = m0 + wave * 16 + q * 4 + r;
            float v = acc[j][r];
            if (rowbias) v += rowbias[(long)bz * M + gm];
            v *= scale;
            long cidx = (long)bz * sC + (long)gm * N + gn;
            if (flags & 1) ((unsigned short*)Cout)[cidx] = f2bf(v);
            else           ((float*)Cout)[cidx] = v;
        }
    }
}

// ---------------- fused fwx GEMM (bt): C1=A1@Bt^T, C2=A2@Bt^T, shared B ----------------
__launch_bounds__(256)
__global__ void k_gemm_fw2(const unsigned short* __restrict__ A1,   // a_fw [B,64,L]
                           const unsigned short* __restrict__ A2,   // b_fw
                           const unsigned short* __restrict__ Bt,   // x_bfT [B,D,L]
                           unsigned short* __restrict__ C1,         // fwx_a [B,64,D]
                           unsigned short* __restrict__ C2)
{
    __shared__ __align__(16) unsigned short As1[64 * 32];
    __shared__ __align__(16) unsigned short As2[64 * 32];
    __shared__ __align__(16) unsigned short Bs[64 * 32];
    const int bz = blockIdx.z;
    const int n0 = blockIdx.x * 64;
    const int tid = threadIdx.x;
    const int wave = tid >> 6, lane = tid & 63;
    const int lrow = tid >> 2, lk = (tid & 3) * 8;
    const int q = lane >> 4, mr = lane & 15;

    const unsigned short* a1p = A1 + ((long)bz * NUM_EXP + lrow) * L_SZ + lk;
    const unsigned short* a2p = A2 + ((long)bz * NUM_EXP + lrow) * L_SZ + lk;
    const unsigned short* bp  = Bt + ((long)bz * D_MODEL + n0 + lrow) * L_SZ + lk;

    floatx4 acc1[4], acc2[4];
    floatx4 z4 = {0.f, 0.f, 0.f, 0.f};
    #pragma unroll
    for (int j = 0; j < 4; j++) { acc1[j] = z4; acc2[j] = z4; }

    for (int k0 = 0; k0 < L_SZ; k0 += 32) {
        __syncthreads();
        *(ushort8*)&As1[lrow * 32 + lk] = *(const ushort8*)(a1p + k0);
        *(ushort8*)&As2[lrow * 32 + lk] = *(const ushort8*)(a2p + k0);
        *(ushort8*)&Bs[lrow * 32 + lk]  = *(const ushort8*)(bp + k0);
        __syncthreads();
        bf16x8 f1 = *(const bf16x8*)&As1[(wave * 16 + mr) * 32 + q * 8];
        bf16x8 f2 = *(const bf16x8*)&As2[(wave * 16 + mr) * 32 + q * 8];
        #pragma unroll
        for (int j = 0; j < 4; j++) {
            bf16x8 bb = *(const bf16x8*)&Bs[(j * 16 + mr) * 32 + q * 8];
            acc1[j] = __builtin_amdgcn_mfma_f32_16x16x32_bf16(f1, bb, acc1[j], 0, 0, 0);
            acc2[j] = __builtin_amdgcn_mfma_f32_16x16x32_bf16(f2, bb, acc2[j], 0, 0, 0);
        }
    }
    #pragma unroll
    for (int j = 0; j < 4; j++) {
        int gn = n0 + j * 16 + mr;
        #pragma unroll
        for (int r = 0; r < 4; r++) {
            int gm = wave * 16 + q * 4 + r;
            long cidx = ((long)bz * NUM_EXP + gm) * D_MODEL + gn;
            C1[cidx] = f2bf(acc1[j][r]);
            C2[cidx] = f2bf(acc2[j][r]);
        }
    }
}

// ---------------- fused cls GEMM (bt): side = blockIdx.z>>4 ----------------
// cls[e,d] = fwx[e,:]·W[d,:] + wsum[e]*bias[d] + biasE[e,d]; split hi/lo, transposed [d,e]
__launch_bounds__(256)
__global__ void k_gemm_cls(const unsigned short* __restrict__ fwxA, const unsigned short* __restrict__ fwxB,
                           const unsigned short* __restrict__ Wa_, const unsigned short* __restrict__ Wb_,
                           const float* __restrict__ ba_, const float* __restrict__ bb_,
                           const float* __restrict__ wsA, const float* __restrict__ wsB,
                           const float* __restrict__ biasE,
                           unsigned short* __restrict__ aHi, unsigned short* __restrict__ aLo,
                           unsigned short* __restrict__ bHi, unsigned short* __restrict__ bLo)
{
    __shared__ __align__(16) unsigned short As[64 * 32];
    __shared__ __align__(16) unsigned short Bs[64 * 32];
    const int zz = blockIdx.z;
    const int side = zz >> 4, bz = zz & 15;
    const unsigned short* Ab = (side ? fwxB : fwxA) + (long)bz * NUM_EXP * D_MODEL;
    const unsigned short* Bb = side ? Wb_ : Wa_;
    const float* cb = side ? bb_ : ba_;
    const float* rw = (side ? wsB : wsA) + bz * NUM_EXP;
    const float* bE = biasE + (long)bz * NUM_EXP * D_MODEL;
    unsigned short* oHi = (side ? bHi : aHi) + (long)bz * NUM_EXP * D_MODEL;
    unsigned short* oLo = (side ? bLo : aLo) + (long)bz * NUM_EXP * D_MODEL;

    const int tid = threadIdx.x;
    const int wave = tid >> 6, lane = tid & 63;
    const int n0 = blockIdx.x * 64;
    const int lrow = tid >> 2, lk = (tid & 3) * 8;
    const int q = lane >> 4, mr = lane & 15;

    floatx4 acc[4];
    floatx4 z4 = {0.f, 0.f, 0.f, 0.f};
    #pragma unroll
    for (int j = 0; j < 4; j++) acc[j] = z4;

    const unsigned short* Aptr = Ab + (long)lrow * D_MODEL + lk;
    const unsigned short* Bptr = Bb + (long)(n0 + lrow) * D_MODEL + lk;

    for (int k0 = 0; k0 < D_MODEL; k0 += 32) {
        __syncthreads();
        *(ushort8*)&As[lrow * 32 + lk] = *(const ushort8*)(Aptr + k0);
        *(ushort8*)&Bs[lrow * 32 + lk] = *(const ushort8*)(Bptr + k0);
        __syncthreads();
        bf16x8 af = *(const bf16x8*)&As[(wave * 16 + mr) * 32 + q * 8];
        #pragma unroll
        for (int j = 0; j < 4; j++) {
            bf16x8 bfr = *(const bf16x8*)&Bs[(j * 16 + mr) * 32 + q * 8];
            acc[j] = __builtin_amdgcn_mfma_f32_16x16x32_bf16(af, bfr, acc[j], 0, 0, 0);
        }
    }
    #pragma unroll
    for (int j = 0; j < 4; j++) {
        int gn = n0 + j * 16 + mr;          // d
        float cbv = cb[gn];
        #pragma unroll
        for (int r = 0; r < 4; r++) {
            int gm = wave * 16 + q * 4 + r; // e
            float v = acc[j][r] + rw[gm] * cbv + bE[(long)gm * D_MODEL + gn];
            unsigned short hi = f2bf(v);
            long tix = (long)gn * NUM_EXP + gm;
            oHi[tix] = hi;
            oLo[tix] = f2bf(v - bf2f(hi));
        }
    }
}

// ---------------- selector GEMM: 128x128, XCD-swizzled, bf16 logits out ----------------
__launch_bounds__(256)
__global__ void k_gemm_sel(const unsigned short* __restrict__ A,
                           const unsigned short* __restrict__ Bm,
                           const float* __restrict__ bias,
                           unsigned short* __restrict__ C)
{
    __shared__ __align__(16) unsigned short As[128 * 32];
    __shared__ __align__(16) unsigned short Bs[128 * 32];
    const int tid = threadIdx.x;
    const int wave = tid >> 6, lane = tid & 63;
    const int q = lane >> 4, mr = lane & 15;
    const int wm = wave & 1, wn = wave >> 1;
    // XCD swizzle: same-XCD consecutive blocks share the A-tile
    const int blk = blockIdx.x;
    const int m0 = ((blk & 7) * 32 + (blk >> 6)) * 128;
    const int n0 = ((blk >> 3) & 7) * 128;

    int rows[2], kofs8[2];
    #pragma unroll
    for (int c = 0; c < 2; c++) {
        int s = c * 256 + tid;
        int row = s >> 2;
        rows[c] = row;
        kofs8[c] = ((s & 3) ^ ((row >> 1) & 3)) * 8;
    }
    const unsigned short* gA0 = A + (long)(m0 + rows[0]) * 1024 + kofs8[0];
    const unsigned short* gA1 = A + (long)(m0 + rows[1]) * 1024 + kofs8[1];
    const unsigned short* gB0 = Bm + (long)(n0 + rows[0]) * 1024 + kofs8[0];
    const unsigned short* gB1 = Bm + (long)(n0 + rows[1]) * 1024 + kofs8[1];
    unsigned short* LA0 = &As[(0 * 256 + wave * 64) * 8];
    unsigned short* LA1 = &As[(1 * 256 + wave * 64) * 8];
    unsigned short* LB0 = &Bs[(0 * 256 + wave * 64) * 8];
    unsigned short* LB1 = &Bs[(1 * 256 + wave * 64) * 8];

    floatx4 acc[4][4];
    floatx4 z4 = {0.f, 0.f, 0.f, 0.f};
    #pragma unroll
    for (int i = 0; i < 4; i++)
        #pragma unroll
        for (int j = 0; j < 4; j++) acc[i][j] = z4;

    const int kread = (q ^ ((mr >> 1) & 3)) * 8;

    for (int k0 = 0; k0 < 1024; k0 += 32) {
        __syncthreads();
        GLD16(gA0 + k0, LA0);
        GLD16(gA1 + k0, LA1);
        GLD16(gB0 + k0, LB0);
        GLD16(gB1 + k0, LB1);
        __syncthreads();
        bf16x8 af[4], bfv[4];
        #pragma unroll
        for (int i = 0; i < 4; i++)
            af[i] = *(const bf16x8*)&As[(wm * 64 + i * 16 + mr) * 32 + kread];
        #pragma unroll
        for (int j = 0; j < 4; j++)
            bfv[j] = *(const bf16x8*)&Bs[(wn * 64 + j * 16 + mr) * 32 + kread];
        #pragma unroll
        for (int i = 0; i < 4; i++)
            #pragma unroll
            for (int j = 0; j < 4; j++)
                acc[i][j] = __builtin_amdgcn_mfma_f32_16x16x32_bf16(af[i], bfv[j], acc[i][j], 0, 0, 0);
    }

    #pragma unroll
    for (int i = 0; i < 4; i++) {
        #pragma unroll
        for (int j = 0; j < 4; j++) {
            int gn = n0 + wn * 64 + j * 16 + mr;
            float cbv = bias[gn];
            #pragma unroll
            for (int r = 0; r < 4; r++) {
                int gm = m0 + wm * 64 + i * 16 + q * 4 + r;
                C[(long)gm * 1024 + gn] = f2bf(acc[i][j][r] + cbv);
            }
        }
    }
}

// ---------------- forward norm over L (masked); wsum = S/(S+eps) ----------------
__global__ void k_fwnorm(const float* __restrict__ z, const int* __restrict__ mask,
                         unsigned short* __restrict__ a_fw, unsigned short* __restrict__ b_fw,
                         float* __restrict__ wsum_a, float* __restrict__ wsum_b)
{
    int be = blockIdx.x;
    int b = be >> 6;
    const float* zr = z + (long)be * L_SZ;
    const int* mr = mask + (long)b * L_SZ;
    int tid = threadIdx.x;
    float sa = 0.f, sb = 0.f;
    for (int l = tid; l < L_SZ; l += 256) {
        float v = zr[l];
        if (mr[l] != 0) { sa += fmaxf(v, 0.f); sb += fmaxf(-v, 0.f); }
    }
    #pragma unroll
    for (int o = 32; o > 0; o >>= 1) { sa += __shfl_down(sa, o); sb += __shfl_down(sb, o); }
    __shared__ float red[8];
    int wave = tid >> 6, lane = tid & 63;
    if (lane == 0) { red[wave] = sa; red[4 + wave] = sb; }
    __syncthreads();
    float ta = red[0] + red[1] + red[2] + red[3];
    float tb = red[4] + red[5] + red[6] + red[7];
    float ia = 1.f / (ta + 1e-9f), ib = 1.f / (tb + 1e-9f);
    if (tid == 0) { wsum_a[be] = ta * ia; wsum_b[be] = tb * ib; }
    for (int l = tid; l < L_SZ; l += 256) {
        float v = zr[l];
        float m = (mr[l] != 0) ? 1.f : 0.f;
        a_fw[(long)be * L_SZ + l] = f2bf(fmaxf(v, 0.f) * m * ia);
        b_fw[(long)be * L_SZ + l] = f2bf(fmaxf(-v, 0.f) * m * ib);
    }
}

// ---------------- backward norm over E (unmasked), bf16 out ----------------
__global__ void k_bwnorm(const float* __restrict__ z, unsigned short* __restrict__ a_bw,
                         unsigned short* __restrict__ b_bw)
{
    int r = blockIdx.x * 256 + threadIdx.x;
    int b = r >> 11, l = r & 2047;
    const float* zb = z + (long)b * NUM_EXP * L_SZ + l;
    float sa = 0.f, sb = 0.f;
    float va[NUM_EXP];
    #pragma unroll 8
    for (int e = 0; e < NUM_EXP; e++) {
        float v = zb[(long)e * L_SZ];
        va[e] = v;
        sa += fmaxf(v, 0.f); sb += fmaxf(-v, 0.f);
    }
    float ia = 1.f / (sa + 1e-9f), ib = 1.f / (sb + 1e-9f);
    unsigned short* ar = a_bw + (long)r * NUM_EXP;
    unsigned short* br = b_bw + (long)r * NUM_EXP;
    #pragma unroll 8
    for (int e = 0; e < NUM_EXP; e++) {
        float v = va[e];
        ar[e] = f2bf(fmaxf(v, 0.f) * ia);
        br[e] = f2bf(fmaxf(-v, 0.f) * ib);
    }
}

// ---------------- final: out = sig(sel)*(aw@clsA) + (1-sig)*(bw@clsB) via MFMA ----------------
__launch_bounds__(256)
__global__ void k_final_mfma(const unsigned short* __restrict__ aw,
                             const unsigned short* __restrict__ bw,
                             const unsigned short* __restrict__ caHi,
                             const unsigned short* __restrict__ caLo,
                             const unsigned short* __restrict__ cbHi,
                             const unsigned short* __restrict__ cbLo,
                             const unsigned short* __restrict__ selbf,   // bf16 logits
                             float* __restrict__ out)
{
    __shared__ __align__(16) unsigned short Aa[64 * 72];
    __shared__ __align__(16) unsigned short Ab[64 * 72];
    __shared__ __align__(16) unsigned short BaH[64 * 72];
    __shared__ __align__(16) unsigned short BaL[64 * 72];
    __shared__ __align__(16) unsigned short BbH[64 * 72];
    __shared__ __align__(16) unsigned short BbL[64 * 72];
    const int bz = blockIdx.z;
    const int l0 = blockIdx.y * 64, d0 = blockIdx.x * 64;
    const int tid = threadIdx.x;
    const int wave = tid >> 6, lane = tid & 63;
    const int q = lane >> 4, mr = lane & 15;

    const unsigned short* awb = aw + ((long)bz * L_SZ + l0) * NUM_EXP;
    const unsigned short* bwb = bw + ((long)bz * L_SZ + l0) * NUM_EXP;
    const long cbase = ((long)bz * D_MODEL + d0) * NUM_EXP;

    #pragma unroll
    for (int c = 0; c < 2; c++) {
        int idx = c * 256 + tid;
        int row = idx >> 3, kc = (idx & 7) * 8;
        int lw = row * 72 + kc;
        long ga = (long)row * NUM_EXP + kc;
        *(ushort8*)&Aa[lw]  = *(const ushort8*)(awb + ga);
        *(ushort8*)&Ab[lw]  = *(const ushort8*)(bwb + ga);
        *(ushort8*)&BaH[lw] = *(const ushort8*)(caHi + cbase + ga);
        *(ushort8*)&BaL[lw] = *(const ushort8*)(caLo + cbase + ga);
        *(ushort8*)&BbH[lw] = *(const ushort8*)(cbHi + cbase + ga);
        *(ushort8*)&BbL[lw] = *(const ushort8*)(cbLo + cbase + ga);
    }
    __syncthreads();

    floatx4 accA[4], accB[4];
    floatx4 z4 = {0.f, 0.f, 0.f, 0.f};
    #pragma unroll
    for (int j = 0; j < 4; j++) { accA[j] = z4; accB[j] = z4; }

    #pragma unroll
    for (int ks = 0; ks < 2; ks++) {
        int ko = ks * 32 + q * 8;
        bf16x8 fa = *(const bf16x8*)&Aa[(wave * 16 + mr) * 72 + ko];
        bf16x8 fb = *(const bf16x8*)&Ab[(wave * 16 + mr) * 72 + ko];
        #pragma unroll
        for (int j = 0; j < 4; j++) {
            int bo = (j * 16 + mr) * 72 + ko;
            accA[j] = __builtin_amdgcn_mfma_f32_16x16x32_bf16(fa, *(const bf16x8*)&BaH[bo], accA[j], 0, 0, 0);
            accA[j] = __builtin_amdgcn_mfma_f32_16x16x32_bf16(fa, *(const bf16x8*)&BaL[bo], accA[j], 0, 0, 0);
            accB[j] = __builtin_amdgcn_mfma_f32_16x16x32_bf16(fb, *(const bf16x8*)&BbH[bo], accB[j], 0, 0, 0);
            accB[j] = __builtin_amdgcn_mfma_f32_16x16x32_bf16(fb, *(const bf16x8*)&BbL[bo], accB[j], 0, 0, 0);
        }
    }

    #pragma unroll
    for (int j = 0; j < 4; j++) {
        #pragma unroll
        for (int r = 0; r < 4; r++) {
            int gl = l0 + wave * 16 + q * 4 + r;
            int gd = d0 + j * 16 + mr;
            long o = ((long)bz * L_SZ + gl) * D_MODEL + gd;
            float s = 1.f / (1.f + __expf(-bf2f(selbf[o])));
            out[o] = s * accA[j][r] + (1.f - s) * accB[j][r];
        }
    }
}

extern "C" void kernel_launch(void* const* d_in, const int* in_sizes, int n_in,
                              void* d_out, int out_size, void* d_ws, size_t ws_size,
                              hipStream_t stream)
{
    const float* x     = (const float*)d_in[0];
    const int*   nidx  = (const int*)d_in[1];
    const int*   mask  = (const int*)d_in[2];
    const float* q_emb = (const float*)d_in[3];
    const float* b_emb = (const float*)d_in[4];
    const float* Wk    = (const float*)d_in[5];
    const float* bk    = (const float*)d_in[6];
    const float* Wa    = (const float*)d_in[7];
    const float* ba    = (const float*)d_in[8];
    const float* Wb    = (const float*)d_in[9];
    const float* bb    = (const float*)d_in[10];
    const float* Ws    = (const float*)d_in[11];
    const float* bs    = (const float*)d_in[12];
    float* out = (float*)d_out;

    constexpr long BLD = (long)B_SZ * L_SZ * D_MODEL;
    constexpr long BEL = (long)B_SZ * NUM_EXP * L_SZ;
    constexpr long BED = (long)B_SZ * NUM_EXP * D_MODEL;
    constexpr long DD  = (long)D_MODEL * D_MODEL;

    char* w = (char*)d_ws;
    size_t off = 0;
    auto carve = [&](size_t bytes) { char* p = w + off; off += (bytes + 255) & ~(size_t)255; return p; };
    unsigned short* x_bf   = (unsigned short*)carve(BLD * 2);
    unsigned short* x_bfT  = (unsigned short*)carve(BLD * 2);  // later reused as sel logits
    unsigned short* wkT_bf = (unsigned short*)carve(DD * 2);
    unsigned short* wa_bf  = (unsigned short*)carve(DD * 2);
    unsigned short* wb_bf  = (unsigned short*)carve(DD * 2);
    unsigned short* ws_bf  = (unsigned short*)carve(DD * 2);
    unsigned short* qexp   = (unsigned short*)carve(BED * 2);
    float*          bias_e = (float*)carve(BED * 4);
    float*          qbk    = (float*)carve(B_SZ * NUM_EXP * 4);
    unsigned short* qk     = (unsigned short*)carve(BED * 2);
    float*          z      = (float*)carve(BEL * 4);
    unsigned short* a_fw   = (unsigned short*)carve(BEL * 2);
    unsigned short* b_fw   = (unsigned short*)carve(BEL * 2);
    float*          wsum_a = (float*)carve(B_SZ * NUM_EXP * 4);
    float*          wsum_b = (float*)carve(B_SZ * NUM_EXP * 4);
    unsigned short* a_bw   = (unsigned short*)carve(BEL * 2);
    unsigned short* b_bw   = (unsigned short*)carve(BEL * 2);
    unsigned short* fwx_a  = (unsigned short*)carve(BED * 2);
    unsigned short* fwx_b  = (unsigned short*)carve(BED * 2);
    unsigned short* caHi   = (unsigned short*)carve(BED * 2);
    unsigned short* caLo   = (unsigned short*)carve(BED * 2);
    unsigned short* cbHi   = (unsigned short*)carve(BED * 2);
    unsigned short* cbLo   = (unsigned short*)carve(BED * 2);
    if (ws_size < off) return;
    unsigned short* selbf = x_bfT;  // x_bfT dead after fw2 GEMM; sel GEMM runs after it

    // 1. conversions / transposes
    k_convx<<<dim3(16, 32, B_SZ), 256, 0, stream>>>(x, x_bf, x_bfT);
    k_transw<<<dim3(16, 16), 256, 0, stream>>>(Wk, wkT_bf);
    k_convert3<<<(3 * DD) / 2048, 256, 0, stream>>>(Wa, Wb, Ws, wa_bf, wb_bf, ws_bf);
    k_gather<<<B_SZ * NUM_EXP, 256, 0, stream>>>(nidx, q_emb, b_emb, bk, qexp, bias_e, qbk);

    // 2. qk[e,n] = sum_d qexp[e,d] * WkT[n,d]   (bf16 out)
    k_gemm_bt<<<dim3(16, 1, B_SZ), 256, 0, stream>>>(qexp, wkT_bf, nullptr, qk,
        NUM_EXP, D_MODEL, D_MODEL, 1.f, 1, (long)NUM_EXP * D_MODEL, 0, (long)NUM_EXP * D_MODEL);

    // 3. z[e,l] = (qk[e,:]·x[l,:] + qbk[e]) / 32  (f32)
    k_gemm_bt<<<dim3(32, 1, B_SZ), 256, 0, stream>>>(qk, x_bf, qbk, z,
        NUM_EXP, L_SZ, D_MODEL, 1.f / 32.f, 0,
        (long)NUM_EXP * D_MODEL, (long)L_SZ * D_MODEL, (long)NUM_EXP * L_SZ);

    // 4. normalizations
    k_fwnorm<<<B_SZ * NUM_EXP, 256, 0, stream>>>(z, mask, a_fw, b_fw, wsum_a, wsum_b);
    k_bwnorm<<<(B_SZ * L_SZ) / 256, 256, 0, stream>>>(z, a_bw, b_bw);

    // 5. fwx_{a,b}[e,c] = sum_l fw[e,l]·xT[c,l]  (fused, shared B)
    k_gemm_fw2<<<dim3(16, 1, B_SZ), 256, 0, stream>>>(a_fw, b_fw, x_bfT, fwx_a, fwx_b);

    // 6. sel logits -> selbf (aliases x_bfT; runs AFTER fw2)
    k_gemm_sel<<<2048, 256, 0, stream>>>(x_bf, ws_bf, bs, selbf);

    // 7. cls (both sides fused), transposed split store
    k_gemm_cls<<<dim3(16, 1, 32), 256, 0, stream>>>(fwx_a, fwx_b, wa_bf, wb_bf, ba, bb,
        wsum_a, wsum_b, bias_e, caHi, caLo, cbHi, cbLo);

    // 8. final blend
    k_final_mfma<<<dim3(16, 32, B_SZ), 256, 0, stream>>>(a_bw, b_bw, caHi, caLo, cbHi, cbLo, selbf, out);
}